// Round 1
// baseline (2297.498 us; speedup 1.0000x reference)
//
#include <hip/hip_runtime.h>
#include <hip/hip_bf16.h>
#include <cstdint>
#include <cstddef>

#define HDIM 64
#define EPS 1e-5f
static const unsigned SENT = 0x007FFFFFu; // flip(-inf)

__device__ __forceinline__ unsigned flipf(float f) {
    unsigned u = __float_as_uint(f);
    return u ^ ((u & 0x80000000u) ? 0xFFFFFFFFu : 0x80000000u);
}

__device__ __forceinline__ float unflip(unsigned u) {
    if (u == SENT) return 0.0f;  // empty segment -> 0 (torch_scatter fill)
    unsigned b = (u & 0x80000000u) ? (u & 0x7FFFFFFFu) : ~u;
    return __uint_as_float(b);
}

// Fill both flipped-max accumulators with the sentinel (= flip(-inf)).
__global__ void init_flip_kernel(uint4* __restrict__ p, size_t n4) {
    uint4 v; v.x = SENT; v.y = SENT; v.z = SENT; v.w = SENT;
    size_t i = (size_t)blockIdx.x * blockDim.x + threadIdx.x;
    size_t stride = (size_t)gridDim.x * blockDim.x;
    for (; i < n4; i += stride) p[i] = v;
}

// 16 threads per edge, each owns 4 columns. 8 atomicMax per thread.
__global__ __launch_bounds__(256) void scatter_max_kernel(
    const int* __restrict__ ei, const float* __restrict__ msg,
    unsigned* __restrict__ fwdf, unsigned* __restrict__ bwdf, int E) {
    long long gid = (long long)blockIdx.x * blockDim.x + threadIdx.x;
    int e = (int)(gid >> 4);
    if (e >= E) return;
    int part = (int)(gid & 15);
    int row = ei[e];
    int col = ei[(size_t)E + e];
    float4 m = *(const float4*)&msg[(size_t)e * HDIM + part * 4];
    unsigned f0 = flipf(m.x), f1 = flipf(m.y), f2 = flipf(m.z), f3 = flipf(m.w);
    unsigned* fd = &fwdf[(size_t)col * HDIM + part * 4];
    unsigned* bd = &bwdf[(size_t)row * HDIM + part * 4];
    atomicMax(fd + 0, f0); atomicMax(fd + 1, f1);
    atomicMax(fd + 2, f2); atomicMax(fd + 3, f3);
    atomicMax(bd + 0, f0); atomicMax(bd + 1, f1);
    atomicMax(bd + 2, f2); atomicMax(bd + 3, f3);
}

// y1 = concat(fwd,bwd) @ W1 + b1   (unflips inputs on the fly)
__global__ __launch_bounds__(256) void gemm1_kernel(
    const unsigned* __restrict__ fwdf, const unsigned* __restrict__ bwdf,
    const float* __restrict__ W1, const float* __restrict__ b1,
    float* __restrict__ y1, int N) {
    __shared__ float Ws[128 * HDIM];
    __shared__ float bs[HDIM];
    for (int i = threadIdx.x; i < 128 * HDIM / 4; i += 256)
        ((float4*)Ws)[i] = ((const float4*)W1)[i];
    if (threadIdx.x < 16)
        ((float4*)bs)[threadIdx.x] = ((const float4*)b1)[threadIdx.x];
    __syncthreads();
    int n = blockIdx.x * 256 + threadIdx.x;
    if (n >= N) return;

    float acc[HDIM];
#pragma unroll
    for (int o = 0; o < HDIM; ++o) acc[o] = bs[o];

#pragma unroll 1
    for (int half = 0; half < 2; ++half) {
        const uint4* p = (const uint4*)((half ? bwdf : fwdf) + (size_t)n * HDIM);
#pragma unroll 1
        for (int kk = 0; kk < 16; ++kk) {
            uint4 u = p[kk];
            float f[4] = { unflip(u.x), unflip(u.y), unflip(u.z), unflip(u.w) };
            const float* w = &Ws[(half * 64 + kk * 4) * HDIM];
#pragma unroll
            for (int j = 0; j < 4; ++j)
#pragma unroll
                for (int o = 0; o < HDIM; ++o)
                    acc[o] = fmaf(f[j], w[j * HDIM + o], acc[o]);
        }
    }
    float4* dst = (float4*)&y1[(size_t)n * HDIM];
#pragma unroll
    for (int o4 = 0; o4 < 16; ++o4) {
        float4 v;
        v.x = acc[o4 * 4 + 0]; v.y = acc[o4 * 4 + 1];
        v.z = acc[o4 * 4 + 2]; v.w = acc[o4 * 4 + 3];
        dst[o4] = v;
    }
}

// Per-column sum & sum-of-squares over a row-major [N,64] matrix.
__global__ __launch_bounds__(256) void colstats_kernel(
    const float* __restrict__ y, float* __restrict__ sum, float* __restrict__ sq, int N) {
    int col = threadIdx.x & 63;
    int grp = threadIdx.x >> 6;              // 0..3
    int stride = gridDim.x * 4;
    float s = 0.f, q = 0.f;
    for (int r = blockIdx.x * 4 + grp; r < N; r += stride) {
        float v = y[(size_t)r * HDIM + col];
        s += v; q += v * v;
    }
    __shared__ float ls[4][HDIM], lq[4][HDIM];
    ls[grp][col] = s; lq[grp][col] = q;
    __syncthreads();
    if (threadIdx.x < HDIM) {
        float S = 0.f, Q = 0.f;
#pragma unroll
        for (int g = 0; g < 4; ++g) { S += ls[g][col]; Q += lq[g][col]; }
        atomicAdd(&sum[col], S);
        atomicAdd(&sq[col], Q);
    }
}

// h1 = relu(BN1(y1)); y2 = h1 @ W2 + b2
__global__ __launch_bounds__(256) void gemm2_kernel(
    const float* __restrict__ y1, const float* __restrict__ sum1, const float* __restrict__ sq1,
    const float* __restrict__ g1, const float* __restrict__ be1,
    const float* __restrict__ W2, const float* __restrict__ b2,
    float* __restrict__ y2, int N) {
    __shared__ float Ws[HDIM * HDIM];
    __shared__ float bs[HDIM], sc[HDIM], sh[HDIM];
    for (int i = threadIdx.x; i < HDIM * HDIM / 4; i += 256)
        ((float4*)Ws)[i] = ((const float4*)W2)[i];
    if (threadIdx.x < 16)
        ((float4*)bs)[threadIdx.x] = ((const float4*)b2)[threadIdx.x];
    if (threadIdx.x < HDIM) {
        int c = threadIdx.x;
        float invN = 1.0f / (float)N;
        float mu = sum1[c] * invN;
        float var = sq1[c] * invN - mu * mu;
        float rstd = rsqrtf(var + EPS);
        float s = rstd * g1[c];
        sc[c] = s;
        sh[c] = be1[c] - mu * s;
    }
    __syncthreads();
    int n = blockIdx.x * 256 + threadIdx.x;
    if (n >= N) return;

    float acc[HDIM];
#pragma unroll
    for (int o = 0; o < HDIM; ++o) acc[o] = bs[o];

    const float4* p = (const float4*)&y1[(size_t)n * HDIM];
#pragma unroll 1
    for (int kk = 0; kk < 16; ++kk) {
        float4 u = p[kk];
        float h[4];
#pragma unroll
        for (int j = 0; j < 4; ++j) {
            int k = kk * 4 + j;
            h[j] = fmaxf(fmaf((&u.x)[j], sc[k], sh[k]), 0.0f);
        }
        const float* w = &Ws[(kk * 4) * HDIM];
#pragma unroll
        for (int j = 0; j < 4; ++j)
#pragma unroll
            for (int o = 0; o < HDIM; ++o)
                acc[o] = fmaf(h[j], w[j * HDIM + o], acc[o]);
    }
    float4* dst = (float4*)&y2[(size_t)n * HDIM];
#pragma unroll
    for (int o4 = 0; o4 < 16; ++o4) {
        float4 v;
        v.x = acc[o4 * 4 + 0]; v.y = acc[o4 * 4 + 1];
        v.z = acc[o4 * 4 + 2]; v.w = acc[o4 * 4 + 3];
        dst[o4] = v;
    }
}

// h2 = relu(BN2(y2)); att = sigmoid(h2 @ Wa + ba)
__global__ __launch_bounds__(256) void final_kernel(
    const float* __restrict__ y2, const float* __restrict__ sum2, const float* __restrict__ sq2,
    const float* __restrict__ g2, const float* __restrict__ be2,
    const float* __restrict__ Wa, const float* __restrict__ ba,
    float* __restrict__ out_h2, float* __restrict__ out_att, int N) {
    __shared__ float sc[HDIM], sh[HDIM], wa[HDIM];
    __shared__ float bav;
    if (threadIdx.x < HDIM) {
        int c = threadIdx.x;
        float invN = 1.0f / (float)N;
        float mu = sum2[c] * invN;
        float var = sq2[c] * invN - mu * mu;
        float rstd = rsqrtf(var + EPS);
        float s = rstd * g2[c];
        sc[c] = s;
        sh[c] = be2[c] - mu * s;
        wa[c] = Wa[c];
    }
    if (threadIdx.x == 0) bav = ba[0];
    __syncthreads();
    int n = blockIdx.x * 256 + threadIdx.x;
    if (n >= N) return;

    const float4* p = (const float4*)&y2[(size_t)n * HDIM];
    float4* dst = (float4*)&out_h2[(size_t)n * HDIM];
    float att = bav;
#pragma unroll 1
    for (int kk = 0; kk < 16; ++kk) {
        float4 u = p[kk];
        float4 hv;
#pragma unroll
        for (int j = 0; j < 4; ++j) {
            int k = kk * 4 + j;
            float h = fmaxf(fmaf((&u.x)[j], sc[k], sh[k]), 0.0f);
            (&hv.x)[j] = h;
            att = fmaf(h, wa[k], att);
        }
        dst[kk] = hv;
    }
    out_att[n] = 1.0f / (1.0f + expf(-att));
}

extern "C" void kernel_launch(void* const* d_in, const int* in_sizes, int n_in,
                              void* d_out, int out_size, void* d_ws, size_t ws_size,
                              hipStream_t stream) {
    const float* x_unused = (const float*)d_in[0];
    const int*   ei   = (const int*)d_in[1];
    const float* msg  = (const float*)d_in[2];
    const float* W1   = (const float*)d_in[3];
    const float* b1   = (const float*)d_in[4];
    const float* g1   = (const float*)d_in[5];
    const float* be1  = (const float*)d_in[6];
    const float* W2   = (const float*)d_in[7];
    const float* b2   = (const float*)d_in[8];
    const float* g2   = (const float*)d_in[9];
    const float* be2  = (const float*)d_in[10];
    const float* Wa   = (const float*)d_in[11];
    const float* ba   = (const float*)d_in[12];
    (void)x_unused;

    const int N = in_sizes[0] / HDIM;
    const int E = in_sizes[1] / 2;

    // workspace layout
    unsigned* fwdf = (unsigned*)d_ws;                       // N*64 u32 (later reused as y2)
    unsigned* bwdf = fwdf + (size_t)N * HDIM;               // N*64 u32
    float* stats   = (float*)(bwdf + (size_t)N * HDIM);     // 256 f32: sum1,sq1,sum2,sq2
    float* y2      = (float*)d_ws;                          // reuse fwd region after gemm1
    float* y1      = (float*)d_out;                         // h2 region staged as y1
    float* out_att = (float*)d_out + (size_t)N * HDIM;

    hipMemsetAsync(stats, 0, 256 * sizeof(float), stream);

    size_t n4 = (size_t)2 * N * HDIM / 4;
    init_flip_kernel<<<2048, 256, 0, stream>>>((uint4*)d_ws, n4);

    long long sthreads = (long long)E * 16;
    int sblocks = (int)((sthreads + 255) / 256);
    scatter_max_kernel<<<sblocks, 256, 0, stream>>>(ei, msg, fwdf, bwdf, E);

    int nblocks = (N + 255) / 256;
    gemm1_kernel<<<nblocks, 256, 0, stream>>>(fwdf, bwdf, W1, b1, y1, N);
    colstats_kernel<<<1024, 256, 0, stream>>>(y1, stats, stats + 64, N);
    gemm2_kernel<<<nblocks, 256, 0, stream>>>(y1, stats, stats + 64, g1, be1, W2, b2, y2, N);
    colstats_kernel<<<1024, 256, 0, stream>>>(y2, stats + 128, stats + 192, N);
    final_kernel<<<nblocks, 256, 0, stream>>>(y2, stats + 128, stats + 192, g2, be2, Wa, ba,
                                              (float*)d_out, out_att, N);
}

// Round 2
// 792.021 us; speedup vs baseline: 2.9008x; 2.9008x over previous
//
#include <hip/hip_runtime.h>
#include <hip/hip_bf16.h>
#include <cstdint>
#include <cstddef>

#define HDIM 64
#define EPS 1e-5f
#define SCAN_BLK 1024   // elements per scan block (256 threads x 4)

// ---------------- CSR build ----------------

// degree count: cnt[0..N) = fwd (by col), cnt[N..2N) = bwd (by row)
__global__ __launch_bounds__(256) void degree_kernel(
    const int* __restrict__ ei, unsigned* __restrict__ cnt, int E, int N) {
    int e = blockIdx.x * 256 + threadIdx.x;
    if (e >= E) return;
    int row = ei[e];
    int col = ei[(size_t)E + e];
    atomicAdd(&cnt[col], 1u);
    atomicAdd(&cnt[N + row], 1u);
}

// per-block sums of cnt
__global__ __launch_bounds__(256) void scan_partials_kernel(
    const unsigned* __restrict__ cnt, unsigned* __restrict__ blockSums, int total) {
    int base = blockIdx.x * SCAN_BLK + threadIdx.x * 4;
    unsigned s = 0;
    if (base + 3 < total) {
        uint4 v = *(const uint4*)&cnt[base];
        s = v.x + v.y + v.z + v.w;
    } else {
        for (int j = 0; j < 4; ++j) if (base + j < total) s += cnt[base + j];
    }
    __shared__ unsigned sm[256];
    sm[threadIdx.x] = s;
    __syncthreads();
    for (int off = 128; off > 0; off >>= 1) {
        if (threadIdx.x < off) sm[threadIdx.x] += sm[threadIdx.x + off];
        __syncthreads();
    }
    if (threadIdx.x == 0) blockSums[blockIdx.x] = sm[0];
}

// exclusive scan of blockSums (nb <= 256), single block
__global__ __launch_bounds__(256) void scan_block_kernel(unsigned* blockSums, int nb) {
    __shared__ unsigned sm[256];
    unsigned v = (threadIdx.x < nb) ? blockSums[threadIdx.x] : 0u;
    sm[threadIdx.x] = v;
    __syncthreads();
    for (int off = 1; off < 256; off <<= 1) {
        unsigned t = (threadIdx.x >= (unsigned)off) ? sm[threadIdx.x - off] : 0u;
        __syncthreads();
        sm[threadIdx.x] += t;
        __syncthreads();
    }
    if (threadIdx.x < nb) blockSums[threadIdx.x] = sm[threadIdx.x] - v; // exclusive
}

// write global exclusive offsets into cursor
__global__ __launch_bounds__(256) void scan_write_kernel(
    const unsigned* __restrict__ cnt, const unsigned* __restrict__ blockSums,
    unsigned* __restrict__ cursor, int total) {
    int base = blockIdx.x * SCAN_BLK + threadIdx.x * 4;
    unsigned v0 = 0, v1 = 0, v2 = 0, v3 = 0;
    if (base + 3 < total) {
        uint4 u = *(const uint4*)&cnt[base];
        v0 = u.x; v1 = u.y; v2 = u.z; v3 = u.w;
    } else {
        if (base + 0 < total) v0 = cnt[base + 0];
        if (base + 1 < total) v1 = cnt[base + 1];
        if (base + 2 < total) v2 = cnt[base + 2];
        if (base + 3 < total) v3 = cnt[base + 3];
    }
    unsigned tsum = v0 + v1 + v2 + v3;
    __shared__ unsigned sm[256];
    sm[threadIdx.x] = tsum;
    __syncthreads();
    for (int off = 1; off < 256; off <<= 1) {
        unsigned t = (threadIdx.x >= (unsigned)off) ? sm[threadIdx.x - off] : 0u;
        __syncthreads();
        sm[threadIdx.x] += t;
        __syncthreads();
    }
    unsigned run = sm[threadIdx.x] - tsum + blockSums[blockIdx.x];
    if (base + 0 < total) cursor[base + 0] = run; run += v0;
    if (base + 1 < total) cursor[base + 1] = run; run += v1;
    if (base + 2 < total) cursor[base + 2] = run; run += v2;
    if (base + 3 < total) cursor[base + 3] = run;
}

// fill edge lists; after this, cursor[slot] == segment end
__global__ __launch_bounds__(256) void fill_kernel(
    const int* __restrict__ ei, unsigned* __restrict__ cursor,
    unsigned* __restrict__ elist, int E, int N) {
    int e = blockIdx.x * 256 + threadIdx.x;
    if (e >= E) return;
    int row = ei[e];
    int col = ei[(size_t)E + e];
    unsigned p1 = atomicAdd(&cursor[col], 1u);
    elist[p1] = (unsigned)e;
    unsigned p2 = atomicAdd(&cursor[N + row], 1u);
    elist[p2] = (unsigned)e;
}

// ---------------- gather max ----------------
// 16 threads per node-direction slot; each owns 4 columns (float4).
__global__ __launch_bounds__(256) void gather_max_kernel(
    const float* __restrict__ msg, const unsigned* __restrict__ cursorEnd,
    const unsigned* __restrict__ cnt, const unsigned* __restrict__ elist,
    float* __restrict__ fwd, float* __restrict__ bwd, int N) {
    long long gid = (long long)blockIdx.x * blockDim.x + threadIdx.x;
    int slot = (int)(gid >> 4);
    if (slot >= 2 * N) return;
    int part = (int)(gid & 15);
    unsigned c = cnt[slot];
    unsigned end = cursorEnd[slot];
    unsigned base = end - c;
    float4 acc;
    acc.x = -INFINITY; acc.y = -INFINITY; acc.z = -INFINITY; acc.w = -INFINITY;
    for (unsigned j = 0; j < c; ++j) {
        unsigned e = elist[base + j];
        float4 m = *(const float4*)&msg[(size_t)e * HDIM + part * 4];
        acc.x = fmaxf(acc.x, m.x);
        acc.y = fmaxf(acc.y, m.y);
        acc.z = fmaxf(acc.z, m.z);
        acc.w = fmaxf(acc.w, m.w);
    }
    if (c == 0) { acc.x = 0.f; acc.y = 0.f; acc.z = 0.f; acc.w = 0.f; }
    float* dstbase = (slot < N) ? &fwd[(size_t)slot * HDIM]
                                : &bwd[(size_t)(slot - N) * HDIM];
    *(float4*)(dstbase + part * 4) = acc;
}

// ---------------- MLP ----------------

// y1 = concat(fwd,bwd) @ W1 + b1
__global__ __launch_bounds__(256) void gemm1_kernel(
    const float* __restrict__ fwd, const float* __restrict__ bwd,
    const float* __restrict__ W1, const float* __restrict__ b1,
    float* __restrict__ y1, int N) {
    __shared__ float Ws[128 * HDIM];
    __shared__ float bs[HDIM];
    for (int i = threadIdx.x; i < 128 * HDIM / 4; i += 256)
        ((float4*)Ws)[i] = ((const float4*)W1)[i];
    if (threadIdx.x < 16)
        ((float4*)bs)[threadIdx.x] = ((const float4*)b1)[threadIdx.x];
    __syncthreads();
    int n = blockIdx.x * 256 + threadIdx.x;
    if (n >= N) return;

    float acc[HDIM];
#pragma unroll
    for (int o = 0; o < HDIM; ++o) acc[o] = bs[o];

#pragma unroll 1
    for (int half = 0; half < 2; ++half) {
        const float4* p = (const float4*)((half ? bwd : fwd) + (size_t)n * HDIM);
#pragma unroll 1
        for (int kk = 0; kk < 16; ++kk) {
            float4 u = p[kk];
            const float* w = &Ws[(half * 64 + kk * 4) * HDIM];
#pragma unroll
            for (int j = 0; j < 4; ++j)
#pragma unroll
                for (int o = 0; o < HDIM; ++o)
                    acc[o] = fmaf((&u.x)[j], w[j * HDIM + o], acc[o]);
        }
    }
    float4* dst = (float4*)&y1[(size_t)n * HDIM];
#pragma unroll
    for (int o4 = 0; o4 < 16; ++o4) {
        float4 v;
        v.x = acc[o4 * 4 + 0]; v.y = acc[o4 * 4 + 1];
        v.z = acc[o4 * 4 + 2]; v.w = acc[o4 * 4 + 3];
        dst[o4] = v;
    }
}

// Per-column sum & sum-of-squares over a row-major [N,64] matrix.
__global__ __launch_bounds__(256) void colstats_kernel(
    const float* __restrict__ y, float* __restrict__ sum, float* __restrict__ sq, int N) {
    int col = threadIdx.x & 63;
    int grp = threadIdx.x >> 6;              // 0..3
    int stride = gridDim.x * 4;
    float s = 0.f, q = 0.f;
    for (int r = blockIdx.x * 4 + grp; r < N; r += stride) {
        float v = y[(size_t)r * HDIM + col];
        s += v; q += v * v;
    }
    __shared__ float ls[4][HDIM], lq[4][HDIM];
    ls[grp][col] = s; lq[grp][col] = q;
    __syncthreads();
    if (threadIdx.x < HDIM) {
        float S = 0.f, Q = 0.f;
#pragma unroll
        for (int g = 0; g < 4; ++g) { S += ls[g][col]; Q += lq[g][col]; }
        atomicAdd(&sum[col], S);
        atomicAdd(&sq[col], Q);
    }
}

// h1 = relu(BN1(y1)); y2 = h1 @ W2 + b2
__global__ __launch_bounds__(256) void gemm2_kernel(
    const float* __restrict__ y1, const float* __restrict__ sum1, const float* __restrict__ sq1,
    const float* __restrict__ g1, const float* __restrict__ be1,
    const float* __restrict__ W2, const float* __restrict__ b2,
    float* __restrict__ y2, int N) {
    __shared__ float Ws[HDIM * HDIM];
    __shared__ float bs[HDIM], sc[HDIM], sh[HDIM];
    for (int i = threadIdx.x; i < HDIM * HDIM / 4; i += 256)
        ((float4*)Ws)[i] = ((const float4*)W2)[i];
    if (threadIdx.x < 16)
        ((float4*)bs)[threadIdx.x] = ((const float4*)b2)[threadIdx.x];
    if (threadIdx.x < HDIM) {
        int c = threadIdx.x;
        float invN = 1.0f / (float)N;
        float mu = sum1[c] * invN;
        float var = sq1[c] * invN - mu * mu;
        float rstd = rsqrtf(var + EPS);
        float s = rstd * g1[c];
        sc[c] = s;
        sh[c] = be1[c] - mu * s;
    }
    __syncthreads();
    int n = blockIdx.x * 256 + threadIdx.x;
    if (n >= N) return;

    float acc[HDIM];
#pragma unroll
    for (int o = 0; o < HDIM; ++o) acc[o] = bs[o];

    const float4* p = (const float4*)&y1[(size_t)n * HDIM];
#pragma unroll 1
    for (int kk = 0; kk < 16; ++kk) {
        float4 u = p[kk];
        float h[4];
#pragma unroll
        for (int j = 0; j < 4; ++j) {
            int k = kk * 4 + j;
            h[j] = fmaxf(fmaf((&u.x)[j], sc[k], sh[k]), 0.0f);
        }
        const float* w = &Ws[(kk * 4) * HDIM];
#pragma unroll
        for (int j = 0; j < 4; ++j)
#pragma unroll
            for (int o = 0; o < HDIM; ++o)
                acc[o] = fmaf(h[j], w[j * HDIM + o], acc[o]);
    }
    float4* dst = (float4*)&y2[(size_t)n * HDIM];
#pragma unroll
    for (int o4 = 0; o4 < 16; ++o4) {
        float4 v;
        v.x = acc[o4 * 4 + 0]; v.y = acc[o4 * 4 + 1];
        v.z = acc[o4 * 4 + 2]; v.w = acc[o4 * 4 + 3];
        dst[o4] = v;
    }
}

// h2 = relu(BN2(y2)); att = sigmoid(h2 @ Wa + ba)
__global__ __launch_bounds__(256) void final_kernel(
    const float* __restrict__ y2, const float* __restrict__ sum2, const float* __restrict__ sq2,
    const float* __restrict__ g2, const float* __restrict__ be2,
    const float* __restrict__ Wa, const float* __restrict__ ba,
    float* __restrict__ out_h2, float* __restrict__ out_att, int N) {
    __shared__ float sc[HDIM], sh[HDIM], wa[HDIM];
    __shared__ float bav;
    if (threadIdx.x < HDIM) {
        int c = threadIdx.x;
        float invN = 1.0f / (float)N;
        float mu = sum2[c] * invN;
        float var = sq2[c] * invN - mu * mu;
        float rstd = rsqrtf(var + EPS);
        float s = rstd * g2[c];
        sc[c] = s;
        sh[c] = be2[c] - mu * s;
        wa[c] = Wa[c];
    }
    if (threadIdx.x == 0) bav = ba[0];
    __syncthreads();
    int n = blockIdx.x * 256 + threadIdx.x;
    if (n >= N) return;

    const float4* p = (const float4*)&y2[(size_t)n * HDIM];
    float4* dst = (float4*)&out_h2[(size_t)n * HDIM];
    float att = bav;
#pragma unroll 1
    for (int kk = 0; kk < 16; ++kk) {
        float4 u = p[kk];
        float4 hv;
#pragma unroll
        for (int j = 0; j < 4; ++j) {
            int k = kk * 4 + j;
            float h = fmaxf(fmaf((&u.x)[j], sc[k], sh[k]), 0.0f);
            (&hv.x)[j] = h;
            att = fmaf(h, wa[k], att);
        }
        dst[kk] = hv;
    }
    out_att[n] = 1.0f / (1.0f + expf(-att));
}

extern "C" void kernel_launch(void* const* d_in, const int* in_sizes, int n_in,
                              void* d_out, int out_size, void* d_ws, size_t ws_size,
                              hipStream_t stream) {
    const int*   ei   = (const int*)d_in[1];
    const float* msg  = (const float*)d_in[2];
    const float* W1   = (const float*)d_in[3];
    const float* b1   = (const float*)d_in[4];
    const float* g1   = (const float*)d_in[5];
    const float* be1  = (const float*)d_in[6];
    const float* W2   = (const float*)d_in[7];
    const float* b2   = (const float*)d_in[8];
    const float* g2   = (const float*)d_in[9];
    const float* be2  = (const float*)d_in[10];
    const float* Wa   = (const float*)d_in[11];
    const float* ba   = (const float*)d_in[12];

    const int N = in_sizes[0] / HDIM;
    const int E = in_sizes[1] / 2;

    // workspace layout
    float*    fwd       = (float*)d_ws;                          // N*64 f32 (reused as y2)
    float*    bwd       = fwd + (size_t)N * HDIM;                // N*64 f32
    unsigned* cnt       = (unsigned*)(bwd + (size_t)N * HDIM);   // 2N u32
    unsigned* cursor    = cnt + (size_t)2 * N;                   // 2N u32
    unsigned* blockSums = cursor + (size_t)2 * N;                // 256 u32
    float*    stats     = (float*)(blockSums + 256);             // 256 f32
    unsigned* elist     = (unsigned*)(stats + 256);              // 2E u32
    float*    y2        = fwd;                                   // reuse after gemm1
    float*    y1        = (float*)d_out;                         // h2 region staged as y1
    float*    out_att   = (float*)d_out + (size_t)N * HDIM;

    // zero cnt + cursor + blockSums + stats in one shot (contiguous)
    hipMemsetAsync(cnt, 0, ((size_t)4 * N + 512) * sizeof(unsigned), stream);

    int eblocks = (E + 255) / 256;
    degree_kernel<<<eblocks, 256, 0, stream>>>(ei, cnt, E, N);

    int total = 2 * N;
    int nscan = (total + SCAN_BLK - 1) / SCAN_BLK;   // 196 for N=100k (must be <=256)
    scan_partials_kernel<<<nscan, 256, 0, stream>>>(cnt, blockSums, total);
    scan_block_kernel<<<1, 256, 0, stream>>>(blockSums, nscan);
    scan_write_kernel<<<nscan, 256, 0, stream>>>(cnt, blockSums, cursor, total);

    fill_kernel<<<eblocks, 256, 0, stream>>>(ei, cursor, elist, E, N);

    int gblocks = (total * 16 + 255) / 256;
    gather_max_kernel<<<gblocks, 256, 0, stream>>>(msg, cursor, cnt, elist, fwd, bwd, N);

    int nblocks = (N + 255) / 256;
    gemm1_kernel<<<nblocks, 256, 0, stream>>>(fwd, bwd, W1, b1, y1, N);
    colstats_kernel<<<1024, 256, 0, stream>>>(y1, stats, stats + 64, N);
    gemm2_kernel<<<nblocks, 256, 0, stream>>>(y1, stats, stats + 64, g1, be1, W2, b2, y2, N);
    colstats_kernel<<<1024, 256, 0, stream>>>(y2, stats + 128, stats + 192, N);
    final_kernel<<<nblocks, 256, 0, stream>>>(y2, stats + 128, stats + 192, g2, be2, Wa, ba,
                                              (float*)d_out, out_att, N);
}

// Round 3
// 591.156 us; speedup vs baseline: 3.8864x; 1.3398x over previous
//
#include <hip/hip_runtime.h>
#include <hip/hip_bf16.h>
#include <cstdint>
#include <cstddef>

#define HDIM 64
#define EPS 1e-5f
#define SCAN_BLK 1024   // elements per scan block (256 threads x 4)

__device__ __forceinline__ unsigned bf16rn(float f) {
    unsigned u = __float_as_uint(f);
    return (u + 0x7FFFu + ((u >> 16) & 1u)) >> 16;   // round-nearest-even
}

// ---------------- CSR build ----------------

// degree count + per-edge rank capture.
// cnt[0..N) = fwd (by col), cnt[N..2N) = bwd (by row)
__global__ __launch_bounds__(256) void degree_rank_kernel(
    const int* __restrict__ ei, unsigned* __restrict__ cnt,
    unsigned* __restrict__ rankF, unsigned* __restrict__ rankB, int E, int N) {
    int e = blockIdx.x * 256 + threadIdx.x;
    if (e >= E) return;
    int row = ei[e];
    int col = ei[(size_t)E + e];
    rankF[e] = atomicAdd(&cnt[col], 1u);
    rankB[e] = atomicAdd(&cnt[N + row], 1u);
}

// plain degree (fallback path)
__global__ __launch_bounds__(256) void degree_kernel(
    const int* __restrict__ ei, unsigned* __restrict__ cnt, int E, int N) {
    int e = blockIdx.x * 256 + threadIdx.x;
    if (e >= E) return;
    int row = ei[e];
    int col = ei[(size_t)E + e];
    atomicAdd(&cnt[col], 1u);
    atomicAdd(&cnt[N + row], 1u);
}

// per-block sums of cnt
__global__ __launch_bounds__(256) void scan_partials_kernel(
    const unsigned* __restrict__ cnt, unsigned* __restrict__ blockSums, int total) {
    int base = blockIdx.x * SCAN_BLK + threadIdx.x * 4;
    unsigned s = 0;
    if (base + 3 < total) {
        uint4 v = *(const uint4*)&cnt[base];
        s = v.x + v.y + v.z + v.w;
    } else {
        for (int j = 0; j < 4; ++j) if (base + j < total) s += cnt[base + j];
    }
    __shared__ unsigned sm[256];
    sm[threadIdx.x] = s;
    __syncthreads();
    for (int off = 128; off > 0; off >>= 1) {
        if (threadIdx.x < off) sm[threadIdx.x] += sm[threadIdx.x + off];
        __syncthreads();
    }
    if (threadIdx.x == 0) blockSums[blockIdx.x] = sm[0];
}

// exclusive scan of blockSums (nb <= 256), single block
__global__ __launch_bounds__(256) void scan_block_kernel(unsigned* blockSums, int nb) {
    __shared__ unsigned sm[256];
    unsigned v = (threadIdx.x < nb) ? blockSums[threadIdx.x] : 0u;
    sm[threadIdx.x] = v;
    __syncthreads();
    for (int off = 1; off < 256; off <<= 1) {
        unsigned t = (threadIdx.x >= (unsigned)off) ? sm[threadIdx.x - off] : 0u;
        __syncthreads();
        sm[threadIdx.x] += t;
        __syncthreads();
    }
    if (threadIdx.x < nb) blockSums[threadIdx.x] = sm[threadIdx.x] - v; // exclusive
}

// write global exclusive offsets into cursor
__global__ __launch_bounds__(256) void scan_write_kernel(
    const unsigned* __restrict__ cnt, const unsigned* __restrict__ blockSums,
    unsigned* __restrict__ cursor, int total) {
    int base = blockIdx.x * SCAN_BLK + threadIdx.x * 4;
    unsigned v0 = 0, v1 = 0, v2 = 0, v3 = 0;
    if (base + 3 < total) {
        uint4 u = *(const uint4*)&cnt[base];
        v0 = u.x; v1 = u.y; v2 = u.z; v3 = u.w;
    } else {
        if (base + 0 < total) v0 = cnt[base + 0];
        if (base + 1 < total) v1 = cnt[base + 1];
        if (base + 2 < total) v2 = cnt[base + 2];
        if (base + 3 < total) v3 = cnt[base + 3];
    }
    unsigned tsum = v0 + v1 + v2 + v3;
    __shared__ unsigned sm[256];
    sm[threadIdx.x] = tsum;
    __syncthreads();
    for (int off = 1; off < 256; off <<= 1) {
        unsigned t = (threadIdx.x >= (unsigned)off) ? sm[threadIdx.x - off] : 0u;
        __syncthreads();
        sm[threadIdx.x] += t;
        __syncthreads();
    }
    unsigned run = sm[threadIdx.x] - tsum + blockSums[blockIdx.x];
    if (base + 0 < total) cursor[base + 0] = run; run += v0;
    if (base + 1 < total) cursor[base + 1] = run; run += v1;
    if (base + 2 < total) cursor[base + 2] = run; run += v2;
    if (base + 3 < total) cursor[base + 3] = run;
}

// ---------------- big path: place bf16 messages in CSR order ----------------
// 16 threads per edge; each converts a float4 to bf16x4 and writes it to the
// fwd and bwd CSR slots (full-line 128B rows, no amplification, no atomics).
__global__ __launch_bounds__(256) void place_msg_kernel(
    const int* __restrict__ ei, const float* __restrict__ msg,
    const unsigned* __restrict__ cursor,
    const unsigned* __restrict__ rankF, const unsigned* __restrict__ rankB,
    unsigned short* __restrict__ sortedMsg, int E, int N) {
    long long gid = (long long)blockIdx.x * 256 + threadIdx.x;
    int e = (int)(gid >> 4);
    if (e >= E) return;
    int part = (int)(gid & 15);
    int row = ei[e];
    int col = ei[(size_t)E + e];
    unsigned posF = cursor[col] + rankF[e];
    unsigned posB = cursor[N + row] + rankB[e];
    float4 m = *(const float4*)&msg[(size_t)e * HDIM + part * 4];
    uint2 b;
    b.x = bf16rn(m.x) | (bf16rn(m.y) << 16);
    b.y = bf16rn(m.z) | (bf16rn(m.w) << 16);
    *(uint2*)&sortedMsg[(size_t)posF * HDIM + part * 4] = b;
    *(uint2*)&sortedMsg[(size_t)posB * HDIM + part * 4] = b;
}

// gather over contiguous bf16 CSR segments
__global__ __launch_bounds__(256) void gather_max_bf16_kernel(
    const unsigned short* __restrict__ sortedMsg,
    const unsigned* __restrict__ cursor, const unsigned* __restrict__ cnt,
    float* __restrict__ fwd, float* __restrict__ bwd, int N) {
    long long gid = (long long)blockIdx.x * 256 + threadIdx.x;
    int slot = (int)(gid >> 4);
    if (slot >= 2 * N) return;
    int part = (int)(gid & 15);
    unsigned base = cursor[slot];
    unsigned c = cnt[slot];
    float4 acc;
    acc.x = -INFINITY; acc.y = -INFINITY; acc.z = -INFINITY; acc.w = -INFINITY;
    const uint2* p = (const uint2*)&sortedMsg[(size_t)base * HDIM + part * 4];
    for (unsigned j = 0; j < c; ++j) {
        uint2 v = p[(size_t)j * (HDIM / 4)];
        acc.x = fmaxf(acc.x, __uint_as_float(v.x << 16));
        acc.y = fmaxf(acc.y, __uint_as_float(v.x & 0xFFFF0000u));
        acc.z = fmaxf(acc.z, __uint_as_float(v.y << 16));
        acc.w = fmaxf(acc.w, __uint_as_float(v.y & 0xFFFF0000u));
    }
    if (c == 0) { acc.x = 0.f; acc.y = 0.f; acc.z = 0.f; acc.w = 0.f; }
    float* dstbase = (slot < N) ? &fwd[(size_t)slot * HDIM]
                                : &bwd[(size_t)(slot - N) * HDIM];
    *(float4*)(dstbase + part * 4) = acc;
}

// ---------------- fallback path (R2): elist fill + f32 gather ----------------

__global__ __launch_bounds__(256) void fill_kernel(
    const int* __restrict__ ei, unsigned* __restrict__ cursor,
    unsigned* __restrict__ elist, int E, int N) {
    int e = blockIdx.x * 256 + threadIdx.x;
    if (e >= E) return;
    int row = ei[e];
    int col = ei[(size_t)E + e];
    unsigned p1 = atomicAdd(&cursor[col], 1u);
    elist[p1] = (unsigned)e;
    unsigned p2 = atomicAdd(&cursor[N + row], 1u);
    elist[p2] = (unsigned)e;
}

__global__ __launch_bounds__(256) void gather_max_kernel(
    const float* __restrict__ msg, const unsigned* __restrict__ cursorEnd,
    const unsigned* __restrict__ cnt, const unsigned* __restrict__ elist,
    float* __restrict__ fwd, float* __restrict__ bwd, int N) {
    long long gid = (long long)blockIdx.x * blockDim.x + threadIdx.x;
    int slot = (int)(gid >> 4);
    if (slot >= 2 * N) return;
    int part = (int)(gid & 15);
    unsigned c = cnt[slot];
    unsigned end = cursorEnd[slot];
    unsigned base = end - c;
    float4 acc;
    acc.x = -INFINITY; acc.y = -INFINITY; acc.z = -INFINITY; acc.w = -INFINITY;
    for (unsigned j = 0; j < c; ++j) {
        unsigned e = elist[base + j];
        float4 m = *(const float4*)&msg[(size_t)e * HDIM + part * 4];
        acc.x = fmaxf(acc.x, m.x);
        acc.y = fmaxf(acc.y, m.y);
        acc.z = fmaxf(acc.z, m.z);
        acc.w = fmaxf(acc.w, m.w);
    }
    if (c == 0) { acc.x = 0.f; acc.y = 0.f; acc.z = 0.f; acc.w = 0.f; }
    float* dstbase = (slot < N) ? &fwd[(size_t)slot * HDIM]
                                : &bwd[(size_t)(slot - N) * HDIM];
    *(float4*)(dstbase + part * 4) = acc;
}

// ---------------- MLP ----------------

__global__ __launch_bounds__(256) void gemm1_kernel(
    const float* __restrict__ fwd, const float* __restrict__ bwd,
    const float* __restrict__ W1, const float* __restrict__ b1,
    float* __restrict__ y1, int N) {
    __shared__ float Ws[128 * HDIM];
    __shared__ float bs[HDIM];
    for (int i = threadIdx.x; i < 128 * HDIM / 4; i += 256)
        ((float4*)Ws)[i] = ((const float4*)W1)[i];
    if (threadIdx.x < 16)
        ((float4*)bs)[threadIdx.x] = ((const float4*)b1)[threadIdx.x];
    __syncthreads();
    int n = blockIdx.x * 256 + threadIdx.x;
    if (n >= N) return;

    float acc[HDIM];
#pragma unroll
    for (int o = 0; o < HDIM; ++o) acc[o] = bs[o];

#pragma unroll 1
    for (int half = 0; half < 2; ++half) {
        const float4* p = (const float4*)((half ? bwd : fwd) + (size_t)n * HDIM);
#pragma unroll 1
        for (int kk = 0; kk < 16; ++kk) {
            float4 u = p[kk];
            const float* w = &Ws[(half * 64 + kk * 4) * HDIM];
#pragma unroll
            for (int j = 0; j < 4; ++j)
#pragma unroll
                for (int o = 0; o < HDIM; ++o)
                    acc[o] = fmaf((&u.x)[j], w[j * HDIM + o], acc[o]);
        }
    }
    float4* dst = (float4*)&y1[(size_t)n * HDIM];
#pragma unroll
    for (int o4 = 0; o4 < 16; ++o4) {
        float4 v;
        v.x = acc[o4 * 4 + 0]; v.y = acc[o4 * 4 + 1];
        v.z = acc[o4 * 4 + 2]; v.w = acc[o4 * 4 + 3];
        dst[o4] = v;
    }
}

__global__ __launch_bounds__(256) void colstats_kernel(
    const float* __restrict__ y, float* __restrict__ sum, float* __restrict__ sq, int N) {
    int col = threadIdx.x & 63;
    int grp = threadIdx.x >> 6;              // 0..3
    int stride = gridDim.x * 4;
    float s = 0.f, q = 0.f;
    for (int r = blockIdx.x * 4 + grp; r < N; r += stride) {
        float v = y[(size_t)r * HDIM + col];
        s += v; q += v * v;
    }
    __shared__ float ls[4][HDIM], lq[4][HDIM];
    ls[grp][col] = s; lq[grp][col] = q;
    __syncthreads();
    if (threadIdx.x < HDIM) {
        float S = 0.f, Q = 0.f;
#pragma unroll
        for (int g = 0; g < 4; ++g) { S += ls[g][col]; Q += lq[g][col]; }
        atomicAdd(&sum[col], S);
        atomicAdd(&sq[col], Q);
    }
}

__global__ __launch_bounds__(256) void gemm2_kernel(
    const float* __restrict__ y1, const float* __restrict__ sum1, const float* __restrict__ sq1,
    const float* __restrict__ g1, const float* __restrict__ be1,
    const float* __restrict__ W2, const float* __restrict__ b2,
    float* __restrict__ y2, int N) {
    __shared__ float Ws[HDIM * HDIM];
    __shared__ float bs[HDIM], sc[HDIM], sh[HDIM];
    for (int i = threadIdx.x; i < HDIM * HDIM / 4; i += 256)
        ((float4*)Ws)[i] = ((const float4*)W2)[i];
    if (threadIdx.x < 16)
        ((float4*)bs)[threadIdx.x] = ((const float4*)b2)[threadIdx.x];
    if (threadIdx.x < HDIM) {
        int c = threadIdx.x;
        float invN = 1.0f / (float)N;
        float mu = sum1[c] * invN;
        float var = sq1[c] * invN - mu * mu;
        float rstd = rsqrtf(var + EPS);
        float s = rstd * g1[c];
        sc[c] = s;
        sh[c] = be1[c] - mu * s;
    }
    __syncthreads();
    int n = blockIdx.x * 256 + threadIdx.x;
    if (n >= N) return;

    float acc[HDIM];
#pragma unroll
    for (int o = 0; o < HDIM; ++o) acc[o] = bs[o];

    const float4* p = (const float4*)&y1[(size_t)n * HDIM];
#pragma unroll 1
    for (int kk = 0; kk < 16; ++kk) {
        float4 u = p[kk];
        float h[4];
#pragma unroll
        for (int j = 0; j < 4; ++j) {
            int k = kk * 4 + j;
            h[j] = fmaxf(fmaf((&u.x)[j], sc[k], sh[k]), 0.0f);
        }
        const float* w = &Ws[(kk * 4) * HDIM];
#pragma unroll
        for (int j = 0; j < 4; ++j)
#pragma unroll
            for (int o = 0; o < HDIM; ++o)
                acc[o] = fmaf(h[j], w[j * HDIM + o], acc[o]);
    }
    float4* dst = (float4*)&y2[(size_t)n * HDIM];
#pragma unroll
    for (int o4 = 0; o4 < 16; ++o4) {
        float4 v;
        v.x = acc[o4 * 4 + 0]; v.y = acc[o4 * 4 + 1];
        v.z = acc[o4 * 4 + 2]; v.w = acc[o4 * 4 + 3];
        dst[o4] = v;
    }
}

__global__ __launch_bounds__(256) void final_kernel(
    const float* __restrict__ y2, const float* __restrict__ sum2, const float* __restrict__ sq2,
    const float* __restrict__ g2, const float* __restrict__ be2,
    const float* __restrict__ Wa, const float* __restrict__ ba,
    float* __restrict__ out_h2, float* __restrict__ out_att, int N) {
    __shared__ float sc[HDIM], sh[HDIM], wa[HDIM];
    __shared__ float bav;
    if (threadIdx.x < HDIM) {
        int c = threadIdx.x;
        float invN = 1.0f / (float)N;
        float mu = sum2[c] * invN;
        float var = sq2[c] * invN - mu * mu;
        float rstd = rsqrtf(var + EPS);
        float s = rstd * g2[c];
        sc[c] = s;
        sh[c] = be2[c] - mu * s;
        wa[c] = Wa[c];
    }
    if (threadIdx.x == 0) bav = ba[0];
    __syncthreads();
    int n = blockIdx.x * 256 + threadIdx.x;
    if (n >= N) return;

    const float4* p = (const float4*)&y2[(size_t)n * HDIM];
    float4* dst = (float4*)&out_h2[(size_t)n * HDIM];
    float att = bav;
#pragma unroll 1
    for (int kk = 0; kk < 16; ++kk) {
        float4 u = p[kk];
        float4 hv;
#pragma unroll
        for (int j = 0; j < 4; ++j) {
            int k = kk * 4 + j;
            float h = fmaxf(fmaf((&u.x)[j], sc[k], sh[k]), 0.0f);
            (&hv.x)[j] = h;
            att = fmaf(h, wa[k], att);
        }
        dst[kk] = hv;
    }
    out_att[n] = 1.0f / (1.0f + expf(-att));
}

extern "C" void kernel_launch(void* const* d_in, const int* in_sizes, int n_in,
                              void* d_out, int out_size, void* d_ws, size_t ws_size,
                              hipStream_t stream) {
    const int*   ei   = (const int*)d_in[1];
    const float* msg  = (const float*)d_in[2];
    const float* W1   = (const float*)d_in[3];
    const float* b1   = (const float*)d_in[4];
    const float* g1   = (const float*)d_in[5];
    const float* be1  = (const float*)d_in[6];
    const float* W2   = (const float*)d_in[7];
    const float* b2   = (const float*)d_in[8];
    const float* g2   = (const float*)d_in[9];
    const float* be2  = (const float*)d_in[10];
    const float* Wa   = (const float*)d_in[11];
    const float* ba   = (const float*)d_in[12];

    const int N = in_sizes[0] / HDIM;
    const int E = in_sizes[1] / 2;

    // common workspace prefix
    float*    fwd       = (float*)d_ws;                          // N*64 f32 (reused as y2)
    float*    bwd       = fwd + (size_t)N * HDIM;                // N*64 f32
    unsigned* cnt       = (unsigned*)(bwd + (size_t)N * HDIM);   // 2N u32
    unsigned* cursor    = cnt + (size_t)2 * N;                   // 2N u32
    unsigned* blockSums = cursor + (size_t)2 * N;                // 256 u32
    float*    stats     = (float*)(blockSums + 256);             // 256 f32
    unsigned* tail      = (unsigned*)(stats + 256);
    float*    y2        = fwd;                                   // reuse after gemm1
    float*    y1        = (float*)d_out;                         // h2 region staged as y1
    float*    out_att   = (float*)d_out + (size_t)N * HDIM;

    size_t prefix_bytes = (size_t)((char*)tail - (char*)d_ws);
    size_t big_need = prefix_bytes + (size_t)2 * E * sizeof(unsigned)      // ranks
                    + (size_t)2 * E * HDIM * sizeof(unsigned short);      // sortedMsg
    bool big = (ws_size >= big_need);

    hipMemsetAsync(cnt, 0, ((size_t)4 * N + 512) * sizeof(unsigned), stream);

    int eblocks = (E + 255) / 256;
    int total = 2 * N;
    int nscan = (total + SCAN_BLK - 1) / SCAN_BLK;   // 196 for N=100k (<=256)
    int gblocks = (total * 16 + 255) / 256;

    if (big) {
        unsigned* rankF = tail;                                  // E u32
        unsigned* rankB = rankF + E;                             // E u32
        unsigned short* sortedMsg = (unsigned short*)(rankB + E);// 2E*64 bf16

        degree_rank_kernel<<<eblocks, 256, 0, stream>>>(ei, cnt, rankF, rankB, E, N);
        scan_partials_kernel<<<nscan, 256, 0, stream>>>(cnt, blockSums, total);
        scan_block_kernel<<<1, 256, 0, stream>>>(blockSums, nscan);
        scan_write_kernel<<<nscan, 256, 0, stream>>>(cnt, blockSums, cursor, total);

        long long pthreads = (long long)E * 16;
        int pblocks = (int)((pthreads + 255) / 256);
        place_msg_kernel<<<pblocks, 256, 0, stream>>>(ei, msg, cursor, rankF, rankB,
                                                      sortedMsg, E, N);
        gather_max_bf16_kernel<<<gblocks, 256, 0, stream>>>(sortedMsg, cursor, cnt,
                                                            fwd, bwd, N);
    } else {
        unsigned* elist = tail;                                  // 2E u32

        degree_kernel<<<eblocks, 256, 0, stream>>>(ei, cnt, E, N);
        scan_partials_kernel<<<nscan, 256, 0, stream>>>(cnt, blockSums, total);
        scan_block_kernel<<<1, 256, 0, stream>>>(blockSums, nscan);
        scan_write_kernel<<<nscan, 256, 0, stream>>>(cnt, blockSums, cursor, total);

        fill_kernel<<<eblocks, 256, 0, stream>>>(ei, cursor, elist, E, N);
        gather_max_kernel<<<gblocks, 256, 0, stream>>>(msg, cursor, cnt, elist,
                                                       fwd, bwd, N);
    }

    int nblocks = (N + 255) / 256;
    gemm1_kernel<<<nblocks, 256, 0, stream>>>(fwd, bwd, W1, b1, y1, N);
    colstats_kernel<<<1024, 256, 0, stream>>>(y1, stats, stats + 64, N);
    gemm2_kernel<<<nblocks, 256, 0, stream>>>(y1, stats, stats + 64, g1, be1, W2, b2, y2, N);
    colstats_kernel<<<1024, 256, 0, stream>>>(y2, stats + 128, stats + 192, N);
    final_kernel<<<nblocks, 256, 0, stream>>>(y2, stats + 128, stats + 192, g2, be2, Wa, ba,
                                              (float*)d_out, out_att, N);
}

// Round 4
// 550.125 us; speedup vs baseline: 4.1763x; 1.0746x over previous
//
#include <hip/hip_runtime.h>
#include <hip/hip_bf16.h>
#include <cstdint>
#include <cstddef>

#define HDIM 64
#define EPS 1e-5f
#define SCAN_BLK 1024   // elements per scan block (256 threads x 4)

typedef short bf16x8 __attribute__((ext_vector_type(8)));   // 8 bf16 = 4 VGPR
typedef float f32x4  __attribute__((ext_vector_type(4)));   // MFMA acc
typedef float f4v    __attribute__((ext_vector_type(4)));   // NT-capable float4
typedef unsigned u2v __attribute__((ext_vector_type(2)));   // NT-capable uint2

__device__ __forceinline__ unsigned bf16rn(float f) {
    unsigned u = __float_as_uint(f);
    return (u + 0x7FFFu + ((u >> 16) & 1u)) >> 16;   // round-nearest-even
}

// ---------------- CSR build ----------------

__global__ __launch_bounds__(256) void degree_rank_kernel(
    const int* __restrict__ ei, unsigned* __restrict__ cnt,
    unsigned* __restrict__ rankF, unsigned* __restrict__ rankB, int E, int N) {
    int e = blockIdx.x * 256 + threadIdx.x;
    if (e >= E) return;
    int row = ei[e];
    int col = ei[(size_t)E + e];
    rankF[e] = atomicAdd(&cnt[col], 1u);
    rankB[e] = atomicAdd(&cnt[N + row], 1u);
}

__global__ __launch_bounds__(256) void degree_kernel(
    const int* __restrict__ ei, unsigned* __restrict__ cnt, int E, int N) {
    int e = blockIdx.x * 256 + threadIdx.x;
    if (e >= E) return;
    atomicAdd(&cnt[ei[(size_t)E + e]], 1u);
    atomicAdd(&cnt[N + ei[e]], 1u);
}

__global__ __launch_bounds__(256) void scan_partials_kernel(
    const unsigned* __restrict__ cnt, unsigned* __restrict__ blockSums, int total) {
    int base = blockIdx.x * SCAN_BLK + threadIdx.x * 4;
    unsigned s = 0;
    if (base + 3 < total) {
        uint4 v = *(const uint4*)&cnt[base];
        s = v.x + v.y + v.z + v.w;
    } else {
        for (int j = 0; j < 4; ++j) if (base + j < total) s += cnt[base + j];
    }
    __shared__ unsigned sm[256];
    sm[threadIdx.x] = s;
    __syncthreads();
    for (int off = 128; off > 0; off >>= 1) {
        if (threadIdx.x < off) sm[threadIdx.x] += sm[threadIdx.x + off];
        __syncthreads();
    }
    if (threadIdx.x == 0) blockSums[blockIdx.x] = sm[0];
}

__global__ __launch_bounds__(256) void scan_block_kernel(unsigned* blockSums, int nb) {
    __shared__ unsigned sm[256];
    unsigned v = (threadIdx.x < nb) ? blockSums[threadIdx.x] : 0u;
    sm[threadIdx.x] = v;
    __syncthreads();
    for (int off = 1; off < 256; off <<= 1) {
        unsigned t = (threadIdx.x >= (unsigned)off) ? sm[threadIdx.x - off] : 0u;
        __syncthreads();
        sm[threadIdx.x] += t;
        __syncthreads();
    }
    if (threadIdx.x < nb) blockSums[threadIdx.x] = sm[threadIdx.x] - v; // exclusive
}

__global__ __launch_bounds__(256) void scan_write_kernel(
    const unsigned* __restrict__ cnt, const unsigned* __restrict__ blockSums,
    unsigned* __restrict__ cursor, int total) {
    int base = blockIdx.x * SCAN_BLK + threadIdx.x * 4;
    unsigned v0 = 0, v1 = 0, v2 = 0, v3 = 0;
    if (base + 3 < total) {
        uint4 u = *(const uint4*)&cnt[base];
        v0 = u.x; v1 = u.y; v2 = u.z; v3 = u.w;
    } else {
        if (base + 0 < total) v0 = cnt[base + 0];
        if (base + 1 < total) v1 = cnt[base + 1];
        if (base + 2 < total) v2 = cnt[base + 2];
        if (base + 3 < total) v3 = cnt[base + 3];
    }
    unsigned tsum = v0 + v1 + v2 + v3;
    __shared__ unsigned sm[256];
    sm[threadIdx.x] = tsum;
    __syncthreads();
    for (int off = 1; off < 256; off <<= 1) {
        unsigned t = (threadIdx.x >= (unsigned)off) ? sm[threadIdx.x - off] : 0u;
        __syncthreads();
        sm[threadIdx.x] += t;
        __syncthreads();
    }
    unsigned run = sm[threadIdx.x] - tsum + blockSums[blockIdx.x];
    if (base + 0 < total) cursor[base + 0] = run; run += v0;
    if (base + 1 < total) cursor[base + 1] = run; run += v1;
    if (base + 2 < total) cursor[base + 2] = run; run += v2;
    if (base + 3 < total) cursor[base + 3] = run;
}

// ---------------- big path: place bf16 messages in CSR order ----------------

__global__ __launch_bounds__(256) void place_msg_kernel(
    const int* __restrict__ ei, const float* __restrict__ msg,
    const unsigned* __restrict__ cursor,
    const unsigned* __restrict__ rankF, const unsigned* __restrict__ rankB,
    unsigned short* __restrict__ sortedMsg, int E, int N) {
    long long gid = (long long)blockIdx.x * 256 + threadIdx.x;
    int e = (int)(gid >> 4);
    if (e >= E) return;
    int part = (int)(gid & 15);
    int row = ei[e];
    int col = ei[(size_t)E + e];
    unsigned posF = cursor[col] + rankF[e];
    unsigned posB = cursor[N + row] + rankB[e];
    f4v m = __builtin_nontemporal_load((const f4v*)&msg[(size_t)e * HDIM + part * 4]);
    u2v b;
    b.x = bf16rn(m.x) | (bf16rn(m.y) << 16);
    b.y = bf16rn(m.z) | (bf16rn(m.w) << 16);
    __builtin_nontemporal_store(b, (u2v*)&sortedMsg[(size_t)posF * HDIM + part * 4]);
    __builtin_nontemporal_store(b, (u2v*)&sortedMsg[(size_t)posB * HDIM + part * 4]);
}

// gather over contiguous bf16 CSR segments -> packed bf16 fwd/bwd
__global__ __launch_bounds__(256) void gather_max_bf16_kernel(
    const unsigned short* __restrict__ sortedMsg,
    const unsigned* __restrict__ cursor, const unsigned* __restrict__ cnt,
    unsigned short* __restrict__ fwdB, unsigned short* __restrict__ bwdB, int N) {
    long long gid = (long long)blockIdx.x * 256 + threadIdx.x;
    int slot = (int)(gid >> 4);
    if (slot >= 2 * N) return;
    int part = (int)(gid & 15);
    unsigned base = cursor[slot];
    unsigned c = cnt[slot];
    float ax = -INFINITY, ay = -INFINITY, az = -INFINITY, aw = -INFINITY;
    const u2v* p = (const u2v*)&sortedMsg[(size_t)base * HDIM + part * 4];
    for (unsigned j = 0; j < c; ++j) {
        u2v v = __builtin_nontemporal_load(p + (size_t)j * (HDIM / 4));
        ax = fmaxf(ax, __uint_as_float(v.x << 16));
        ay = fmaxf(ay, __uint_as_float(v.x & 0xFFFF0000u));
        az = fmaxf(az, __uint_as_float(v.y << 16));
        aw = fmaxf(aw, __uint_as_float(v.y & 0xFFFF0000u));
    }
    if (c == 0) { ax = 0.f; ay = 0.f; az = 0.f; aw = 0.f; }
    u2v o;
    o.x = bf16rn(ax) | (bf16rn(ay) << 16);   // exact: max of bf16 values
    o.y = bf16rn(az) | (bf16rn(aw) << 16);
    unsigned short* dst = (slot < N) ? &fwdB[(size_t)slot * HDIM]
                                     : &bwdB[(size_t)(slot - N) * HDIM];
    *(u2v*)(dst + part * 4) = o;
}

// ---------------- fallback path: elist fill + f32 gather -> bf16 out ----------------

__global__ __launch_bounds__(256) void fill_kernel(
    const int* __restrict__ ei, unsigned* __restrict__ cursor,
    unsigned* __restrict__ elist, int E, int N) {
    int e = blockIdx.x * 256 + threadIdx.x;
    if (e >= E) return;
    int row = ei[e];
    int col = ei[(size_t)E + e];
    unsigned p1 = atomicAdd(&cursor[col], 1u);
    elist[p1] = (unsigned)e;
    unsigned p2 = atomicAdd(&cursor[N + row], 1u);
    elist[p2] = (unsigned)e;
}

__global__ __launch_bounds__(256) void gather_max_f32_kernel(
    const float* __restrict__ msg, const unsigned* __restrict__ cursorEnd,
    const unsigned* __restrict__ cnt, const unsigned* __restrict__ elist,
    unsigned short* __restrict__ fwdB, unsigned short* __restrict__ bwdB, int N) {
    long long gid = (long long)blockIdx.x * 256 + threadIdx.x;
    int slot = (int)(gid >> 4);
    if (slot >= 2 * N) return;
    int part = (int)(gid & 15);
    unsigned c = cnt[slot];
    unsigned base = cursorEnd[slot] - c;
    float ax = -INFINITY, ay = -INFINITY, az = -INFINITY, aw = -INFINITY;
    for (unsigned j = 0; j < c; ++j) {
        unsigned e = elist[base + j];
        f4v m = *(const f4v*)&msg[(size_t)e * HDIM + part * 4];
        ax = fmaxf(ax, m.x); ay = fmaxf(ay, m.y);
        az = fmaxf(az, m.z); aw = fmaxf(aw, m.w);
    }
    if (c == 0) { ax = 0.f; ay = 0.f; az = 0.f; aw = 0.f; }
    u2v o;
    o.x = bf16rn(ax) | (bf16rn(ay) << 16);
    o.y = bf16rn(az) | (bf16rn(aw) << 16);
    unsigned short* dst = (slot < N) ? &fwdB[(size_t)slot * HDIM]
                                     : &bwdB[(size_t)(slot - N) * HDIM];
    *(u2v*)(dst + part * 4) = o;
}

// ---------------- MLP (MFMA bf16) ----------------

// W1T[o][k] = bf16(W1[k][o]) (128x64 -> 64x128); W2T likewise 64x64
__global__ __launch_bounds__(256) void prep_w_kernel(
    const float* __restrict__ W1, const float* __restrict__ W2,
    unsigned short* __restrict__ W1T, unsigned short* __restrict__ W2T) {
    int t = blockIdx.x * 256 + threadIdx.x;
    if (t < 128 * 64) {
        int k = t >> 6, o = t & 63;
        W1T[o * 128 + k] = (unsigned short)bf16rn(W1[t]);
    } else {
        int t2 = t - 128 * 64;
        if (t2 < 64 * 64) {
            int k = t2 >> 6, o = t2 & 63;
            W2T[o * 64 + k] = (unsigned short)bf16rn(W2[t2]);
        }
    }
}

// y1 = concat(fwd,bwd) @ W1 + b1, fused column stats.
// mfma_f32_16x16x32_bf16 layouts (m89-verified):
//   A: row=lane&15, k=(lane>>4)*8+j ; B: col=lane&15, k=(lane>>4)*8+j
//   C/D: col=lane&15, row=(lane>>4)*4+reg
__global__ __launch_bounds__(256) void gemm1_mfma_kernel(
    const unsigned short* __restrict__ fwdB, const unsigned short* __restrict__ bwdB,
    const unsigned short* __restrict__ W1T, const float* __restrict__ b1,
    float* __restrict__ y1, float* __restrict__ sum1, float* __restrict__ sq1, int N) {
    __shared__ float wsum[4][64], wsq[4][64];
    int tid = threadIdx.x;
    int wave = tid >> 6, lane = tid & 63;
    int lrow = lane & 15, kseg = lane >> 4;
    int rbase = blockIdx.x * 64 + wave * 16;

    bf16x8 bfr[4][4];
#pragma unroll
    for (int nt = 0; nt < 4; ++nt)
#pragma unroll
        for (int kb = 0; kb < 4; ++kb)
            bfr[nt][kb] = *(const bf16x8*)(W1T + (size_t)(nt * 16 + lrow) * 128 + kb * 32 + kseg * 8);

    int r = rbase + lrow;
    bool ok = (r < N);
    size_t ro = (size_t)(ok ? r : 0) * HDIM;
    bf16x8 z = {};
    bf16x8 afr[4];
    afr[0] = *(const bf16x8*)(fwdB + ro + kseg * 8);
    afr[1] = *(const bf16x8*)(fwdB + ro + 32 + kseg * 8);
    afr[2] = *(const bf16x8*)(bwdB + ro + kseg * 8);
    afr[3] = *(const bf16x8*)(bwdB + ro + 32 + kseg * 8);
    if (!ok) { afr[0] = z; afr[1] = z; afr[2] = z; afr[3] = z; }

    f32x4 acc[4] = {};
#pragma unroll
    for (int kb = 0; kb < 4; ++kb)
#pragma unroll
        for (int nt = 0; nt < 4; ++nt)
            acc[nt] = __builtin_amdgcn_mfma_f32_16x16x32_bf16(afr[kb], bfr[nt][kb], acc[nt], 0, 0, 0);

#pragma unroll
    for (int nt = 0; nt < 4; ++nt) {
        int col = nt * 16 + lrow;
        float bias = b1[col];
        float s = 0.f, q = 0.f;
#pragma unroll
        for (int rr = 0; rr < 4; ++rr) {
            int row = rbase + kseg * 4 + rr;
            if (row < N) {
                float v = acc[nt][rr] + bias;
                y1[(size_t)row * HDIM + col] = v;
                s += v; q += v * v;
            }
        }
        s += __shfl_xor(s, 16); s += __shfl_xor(s, 32);
        q += __shfl_xor(q, 16); q += __shfl_xor(q, 32);
        if (kseg == 0) { wsum[wave][col] = s; wsq[wave][col] = q; }
    }
    __syncthreads();
    if (tid < 64) {
        float S = wsum[0][tid] + wsum[1][tid] + wsum[2][tid] + wsum[3][tid];
        float Q = wsq[0][tid] + wsq[1][tid] + wsq[2][tid] + wsq[3][tid];
        atomicAdd(&sum1[tid], S);
        atomicAdd(&sq1[tid], Q);
    }
}

// h1 = relu(BN1(y1)) (bf16); y2 = h1 @ W2 + b2; fused column stats.
__global__ __launch_bounds__(256) void gemm2_mfma_kernel(
    const float* __restrict__ y1, const float* __restrict__ sum1, const float* __restrict__ sq1,
    const float* __restrict__ g1, const float* __restrict__ be1,
    const unsigned short* __restrict__ W2T, const float* __restrict__ b2,
    float* __restrict__ y2, float* __restrict__ sum2, float* __restrict__ sq2, int N) {
    __shared__ float sc[64], sh[64];
    __shared__ float wsum[4][64], wsq[4][64];
    int tid = threadIdx.x;
    if (tid < 64) {
        float invN = 1.0f / (float)N;
        float mu = sum1[tid] * invN;
        float var = sq1[tid] * invN - mu * mu;
        float rs = rsqrtf(var + EPS);
        float s = rs * g1[tid];
        sc[tid] = s;
        sh[tid] = be1[tid] - mu * s;
    }
    __syncthreads();
    int wave = tid >> 6, lane = tid & 63;
    int lrow = lane & 15, kseg = lane >> 4;
    int rbase = blockIdx.x * 64 + wave * 16;

    bf16x8 bfr[4][2];
#pragma unroll
    for (int nt = 0; nt < 4; ++nt)
#pragma unroll
        for (int kb = 0; kb < 2; ++kb)
            bfr[nt][kb] = *(const bf16x8*)(W2T + (size_t)(nt * 16 + lrow) * 64 + kb * 32 + kseg * 8);

    int r = rbase + lrow;
    size_t ro = (size_t)((r < N) ? r : 0) * HDIM;
    bf16x8 afr[2];
#pragma unroll
    for (int kb = 0; kb < 2; ++kb) {
        const f4v* yp = (const f4v*)(y1 + ro + kb * 32 + kseg * 8);
        f4v u0 = yp[0], u1 = yp[1];
        int k0 = kb * 32 + kseg * 8;
        bf16x8 a;
#pragma unroll
        for (int j = 0; j < 4; ++j) {
            float h0 = fmaxf(fmaf(u0[j], sc[k0 + j], sh[k0 + j]), 0.f);
            float h1 = fmaxf(fmaf(u1[j], sc[k0 + 4 + j], sh[k0 + 4 + j]), 0.f);
            a[j] = (short)bf16rn(h0);
            a[4 + j] = (short)bf16rn(h1);
        }
        afr[kb] = a;
    }

    f32x4 acc[4] = {};
#pragma unroll
    for (int kb = 0; kb < 2; ++kb)
#pragma unroll
        for (int nt = 0; nt < 4; ++nt)
            acc[nt] = __builtin_amdgcn_mfma_f32_16x16x32_bf16(afr[kb], bfr[nt][kb], acc[nt], 0, 0, 0);

#pragma unroll
    for (int nt = 0; nt < 4; ++nt) {
        int col = nt * 16 + lrow;
        float bias = b2[col];
        float s = 0.f, q = 0.f;
#pragma unroll
        for (int rr = 0; rr < 4; ++rr) {
            int row = rbase + kseg * 4 + rr;
            if (row < N) {
                float v = acc[nt][rr] + bias;
                y2[(size_t)row * HDIM + col] = v;
                s += v; q += v * v;
            }
        }
        s += __shfl_xor(s, 16); s += __shfl_xor(s, 32);
        q += __shfl_xor(q, 16); q += __shfl_xor(q, 32);
        if (kseg == 0) { wsum[wave][col] = s; wsq[wave][col] = q; }
    }
    __syncthreads();
    if (tid < 64) {
        float S = wsum[0][tid] + wsum[1][tid] + wsum[2][tid] + wsum[3][tid];
        float Q = wsq[0][tid] + wsq[1][tid] + wsq[2][tid] + wsq[3][tid];
        atomicAdd(&sum2[tid], S);
        atomicAdd(&sq2[tid], Q);
    }
}

// h2 = relu(BN2(y2)); att = sigmoid(h2 @ Wa + ba)
__global__ __launch_bounds__(256) void final_kernel(
    const float* __restrict__ y2, const float* __restrict__ sum2, const float* __restrict__ sq2,
    const float* __restrict__ g2, const float* __restrict__ be2,
    const float* __restrict__ Wa, const float* __restrict__ ba,
    float* __restrict__ out_h2, float* __restrict__ out_att, int N) {
    __shared__ float sc[HDIM], sh[HDIM], wa[HDIM];
    __shared__ float bav;
    if (threadIdx.x < HDIM) {
        int c = threadIdx.x;
        float invN = 1.0f / (float)N;
        float mu = sum2[c] * invN;
        float var = sq2[c] * invN - mu * mu;
        float rstd = rsqrtf(var + EPS);
        float s = rstd * g2[c];
        sc[c] = s;
        sh[c] = be2[c] - mu * s;
        wa[c] = Wa[c];
    }
    if (threadIdx.x == 0) bav = ba[0];
    __syncthreads();
    int n = blockIdx.x * 256 + threadIdx.x;
    if (n >= N) return;

    const f4v* p = (const f4v*)&y2[(size_t)n * HDIM];
    f4v* dst = (f4v*)&out_h2[(size_t)n * HDIM];
    float att = bav;
#pragma unroll 1
    for (int kk = 0; kk < 16; ++kk) {
        f4v u = p[kk];
        f4v hv;
#pragma unroll
        for (int j = 0; j < 4; ++j) {
            int k = kk * 4 + j;
            float h = fmaxf(fmaf(u[j], sc[k], sh[k]), 0.0f);
            hv[j] = h;
            att = fmaf(h, wa[k], att);
        }
        dst[kk] = hv;
    }
    out_att[n] = 1.0f / (1.0f + expf(-att));
}

extern "C" void kernel_launch(void* const* d_in, const int* in_sizes, int n_in,
                              void* d_out, int out_size, void* d_ws, size_t ws_size,
                              hipStream_t stream) {
    const int*   ei   = (const int*)d_in[1];
    const float* msg  = (const float*)d_in[2];
    const float* W1   = (const float*)d_in[3];
    const float* b1   = (const float*)d_in[4];
    const float* g1   = (const float*)d_in[5];
    const float* be1  = (const float*)d_in[6];
    const float* W2   = (const float*)d_in[7];
    const float* b2   = (const float*)d_in[8];
    const float* g2   = (const float*)d_in[9];
    const float* be2  = (const float*)d_in[10];
    const float* Wa   = (const float*)d_in[11];
    const float* ba   = (const float*)d_in[12];

    const int N = in_sizes[0] / HDIM;
    const int E = in_sizes[1] / 2;

    // workspace prefix (common)
    unsigned short* fwdB = (unsigned short*)d_ws;                 // N*64 bf16
    unsigned short* bwdB = fwdB + (size_t)N * HDIM;               // N*64 bf16
    unsigned* cnt        = (unsigned*)(bwdB + (size_t)N * HDIM);  // 2N u32
    unsigned* cursor     = cnt + (size_t)2 * N;                   // 2N u32
    unsigned* blockSums  = cursor + (size_t)2 * N;                // 256 u32
    float*    stats      = (float*)(blockSums + 256);             // 256 f32
    unsigned short* W1T  = (unsigned short*)(stats + 256);        // 8192 bf16
    unsigned short* W2T  = W1T + 8192;                            // 4096 bf16
    unsigned* tail       = (unsigned*)(W2T + 4096);
    float*    y1         = (float*)d_out;                         // h2 region staged as y1
    float*    y2         = (float*)d_ws;                          // overlays fwdB+bwdB (25.6MB)
    float*    out_att    = (float*)d_out + (size_t)N * HDIM;

    size_t prefix_bytes = (size_t)((char*)tail - (char*)d_ws);
    size_t big_need = prefix_bytes + (size_t)2 * E * sizeof(unsigned)
                    + (size_t)2 * E * HDIM * sizeof(unsigned short);
    bool big = (ws_size >= big_need);

    // zero cnt + cursor + blockSums + stats (contiguous)
    hipMemsetAsync(cnt, 0, ((size_t)4 * N + 512) * sizeof(unsigned), stream);
    prep_w_kernel<<<48, 256, 0, stream>>>(W1, W2, W1T, W2T);

    int eblocks = (E + 255) / 256;
    int total = 2 * N;
    int nscan = (total + SCAN_BLK - 1) / SCAN_BLK;   // 196 for N=100k (<=256)
    int gblocks = (total * 16 + 255) / 256;

    if (big) {
        unsigned* rankF = tail;                                   // E u32
        unsigned* rankB = rankF + E;                              // E u32
        unsigned short* sortedMsg = (unsigned short*)(rankB + E); // 2E*64 bf16

        degree_rank_kernel<<<eblocks, 256, 0, stream>>>(ei, cnt, rankF, rankB, E, N);
        scan_partials_kernel<<<nscan, 256, 0, stream>>>(cnt, blockSums, total);
        scan_block_kernel<<<1, 256, 0, stream>>>(blockSums, nscan);
        scan_write_kernel<<<nscan, 256, 0, stream>>>(cnt, blockSums, cursor, total);

        long long pthreads = (long long)E * 16;
        int pblocks = (int)((pthreads + 255) / 256);
        place_msg_kernel<<<pblocks, 256, 0, stream>>>(ei, msg, cursor, rankF, rankB,
                                                      sortedMsg, E, N);
        gather_max_bf16_kernel<<<gblocks, 256, 0, stream>>>(sortedMsg, cursor, cnt,
                                                            fwdB, bwdB, N);
    } else {
        unsigned* elist = tail;                                   // 2E u32

        degree_kernel<<<eblocks, 256, 0, stream>>>(ei, cnt, E, N);
        scan_partials_kernel<<<nscan, 256, 0, stream>>>(cnt, blockSums, total);
        scan_block_kernel<<<1, 256, 0, stream>>>(blockSums, nscan);
        scan_write_kernel<<<nscan, 256, 0, stream>>>(cnt, blockSums, cursor, total);

        fill_kernel<<<eblocks, 256, 0, stream>>>(ei, cursor, elist, E, N);
        gather_max_f32_kernel<<<gblocks, 256, 0, stream>>>(msg, cursor, cnt, elist,
                                                           fwdB, bwdB, N);
    }

    int G = (N + 63) / 64;
    gemm1_mfma_kernel<<<G, 256, 0, stream>>>(fwdB, bwdB, W1T, b1, y1,
                                             stats, stats + 64, N);
    gemm2_mfma_kernel<<<G, 256, 0, stream>>>(y1, stats, stats + 64, g1, be1,
                                             W2T, b2, y2, stats + 128, stats + 192, N);
    final_kernel<<<(N + 255) / 256, 256, 0, stream>>>(y2, stats + 128, stats + 192,
                                                      g2, be2, Wa, ba,
                                                      (float*)d_out, out_att, N);
}